// Round 10
// baseline (42509.601 us; speedup 1.0000x reference)
//
#include <hip/hip_runtime.h>
#include <hip/hip_fp16.h>

#define BB 64
#define SS 512
#define DD 1024
#define HH 1024
#define NBLK 128
#define HMASK 63

typedef _Float16 f16;
typedef unsigned long long u64;
typedef __attribute__((ext_vector_type(8))) _Float16 f16x8;
typedef __attribute__((ext_vector_type(4))) _Float16 f16x4;
typedef __attribute__((ext_vector_type(4))) float f32x4;

struct GruWS {
  unsigned sigT[4 * 32 * 16];   // per-(role,member) signal line (64B); value = completed s+1, monotone
  u64 times[4 * 32];            // [phase][role1-member] accumulated s_memrealtime ticks (10ns)
  f16 gi0[4][3 * HH][BB];       // [slot s&3][3H][B]  (uncached path, single consumer)
  f16 gi1[4][3 * HH][BB];
  f16 h0h[64][BB][HH];          // [slot s&63][B][H]  (atomic-swap stores, sc0-cached reads)
  f16 h1h[64][BB][HH];
};

// ---- communication primitives ----
__device__ __forceinline__ f16x8 ld_sys_16B(const void* p) {          // uncached (MALL)
  f16x8 r;
  asm volatile("global_load_dwordx4 %0, %1, off sc0 sc1" : "=v"(r) : "v"(p) : "memory");
  return r;
}
__device__ __forceinline__ f16x8 ld_dev_16B(const void* p) {          // L2-cached, L1-bypass
  f16x8 r;
  asm volatile("global_load_dwordx4 %0, %1, off sc0" : "=v"(r) : "v"(p) : "memory");
  return r;
}
__device__ __forceinline__ void st_sys_16B(void* p, f16x8 v) {
  asm volatile("global_store_dwordx4 %0, %1, off sc0 sc1" :: "v"(p), "v"(v) : "memory");
}
__device__ __forceinline__ void st_sys_8B_u64(void* p, u64 q) {
  asm volatile("global_store_dwordx2 %0, %1, off sc0 sc1" :: "v"(p), "v"(q) : "memory");
}
// h stores: atomic swaps execute AT the MALL -> line stays resident for readers' L2 misses
__device__ __forceinline__ void st_mall_16B(void* p, f16x8 v) {
  union { f16x8 v; u64 q[2]; } u; u.v = v;
  asm volatile("global_atomic_swap_x2 %0, %1, off sc1" :: "v"((u64*)p), "v"(u.q[0]) : "memory");
  asm volatile("global_atomic_swap_x2 %0, %1, off sc1" :: "v"((u64*)p + 1), "v"(u.q[1]) : "memory");
}
__device__ __forceinline__ void st_mall_8B(void* p, u64 q) {
  asm volatile("global_atomic_swap_x2 %0, %1, off sc1" :: "v"((u64*)p), "v"(q) : "memory");
}
__device__ __forceinline__ void sig_swap(unsigned* p, unsigned v) {
  asm volatile("global_atomic_swap %0, %1, off sc1" :: "v"(p), "v"(v) : "memory");
}
__device__ __forceinline__ void drain_vm() {
  asm volatile("s_waitcnt vmcnt(0)" ::: "memory");
  __builtin_amdgcn_sched_barrier(0);
}
__device__ __forceinline__ f16x4 ld_sys_f16x4(const f16* p) {
  u64 q = __hip_atomic_load((const u64*)p, __ATOMIC_RELAXED, __HIP_MEMORY_SCOPE_SYSTEM);
  union { u64 q; f16x4 v; } u; u.q = q; return u.v;
}
__device__ __forceinline__ float ld_sys_f16s(const f16* p) {
  unsigned short s = __hip_atomic_load((const unsigned short*)p, __ATOMIC_RELAXED, __HIP_MEMORY_SCOPE_SYSTEM);
  union { unsigned short s; f16 h; } u; u.s = s; return (float)u.h;
}
__device__ __forceinline__ void nap(int it) {
  if (it < 3) __builtin_amdgcn_s_sleep(1);
  else        __builtin_amdgcn_s_sleep(16);
}

__device__ __forceinline__ void wait1(const unsigned* p, int target, int& seen) {
  if (target <= 0 || seen >= target) return;
  int it = 0;
  for (;;) {
    unsigned v;
    asm volatile("global_load_dword %0, %1, off sc0 sc1" : "=v"(v) : "v"(p));
    asm volatile("s_waitcnt vmcnt(0)" ::: "memory");
    if ((int)v >= target) { seen = (int)v; break; }
    nap(++it);
  }
  asm volatile("" ::: "memory");
}

__device__ __forceinline__ void wait32(const unsigned* rowbase, int target, int lane, int& seen) {
  if (target <= 0 || seen >= target) return;
  const unsigned* p = rowbase + (lane & 31) * 16;
  int it = 0;
  unsigned v;
  for (;;) {
    asm volatile("global_load_dword %0, %1, off sc0 sc1" : "=v"(v) : "v"(p));
    asm volatile("s_waitcnt vmcnt(0)" ::: "memory");
    if (__all((int)v >= target)) break;
    nap(++it);
  }
  int m = (int)v;
#pragma unroll
  for (int off = 1; off < 32; off <<= 1) {
    int o = __shfl_xor(m, off);
    m = (o < m) ? o : m;
  }
  seen = m;
  asm volatile("" ::: "memory");
}

__global__ void gru_init(const float* __restrict__ h0, GruWS* __restrict__ ws) {
  int i = blockIdx.x * 256 + threadIdx.x;
  int j = i * 4;
  if (j < 2 * BB * HH) {
    union { f16 h[4]; u64 q; } u;
#pragma unroll
    for (int k = 0; k < 4; ++k) u.h[k] = (f16)h0[j + k];
    if (j < BB * HH) st_mall_8B(&ws->h0h[HMASK][0][j], u.q);          // slot 63 = state of s=-1
    else             st_mall_8B(&ws->h1h[HMASK][0][j - BB * HH], u.q);
  }
  if (i < 4 * 32)
    __hip_atomic_store(&ws->sigT[i * 16], 0u, __ATOMIC_RELAXED, __HIP_MEMORY_SCOPE_SYSTEM);
}

// diagnostic: spin 6ms + avg(phase total) in realtime (100MHz) units.
// probe dur_us - 6000 = per-block accumulated phase time over 512 ticks.
__global__ void spin_probe(const GruWS* __restrict__ ws, int phase) {
  if (threadIdx.x == 0) {
    u64 sum = 0;
    for (int i = 0; i < 32; ++i)
      sum += __hip_atomic_load(&ws->times[phase * 32 + i], __ATOMIC_RELAXED, __HIP_MEMORY_SCOPE_SYSTEM);
    u64 target = 600000ull + sum / 32;     // 6ms floor + phase avg (10ns ticks)
    u64 t0 = __builtin_amdgcn_s_memrealtime();
    while (__builtin_amdgcn_s_memrealtime() - t0 < target) __builtin_amdgcn_s_sleep(8);
  }
}

__device__ __forceinline__ void mma_pass(const f16x8 areg[8][4], const f16x8* bnt,
                                         float* red, int lane, int wave, f32x4 acc[3]) {
  f32x4 pacc[4][3];
#pragma unroll
  for (int m = 0; m < 4; ++m)
#pragma unroll
    for (int g = 0; g < 3; ++g) pacc[m][g] = (f32x4){0.f, 0.f, 0.f, 0.f};
#pragma unroll
  for (int kk = 0; kk < 8; ++kk)
#pragma unroll
    for (int m = 0; m < 4; ++m)
#pragma unroll
      for (int g = 0; g < 3; ++g)
        pacc[m][g] = __builtin_amdgcn_mfma_f32_16x16x32_f16(areg[kk][m], bnt[g * 8 + kk], pacc[m][g], 0, 0, 0);
#pragma unroll
  for (int m = 0; m < 4; ++m)
    if (m != wave)
#pragma unroll
      for (int g = 0; g < 3; ++g)
#pragma unroll
        for (int r = 0; r < 4; ++r)
          red[(((wave * 4 + m) * 3 + g) * 4 + r) * 64 + lane] = pacc[m][g][r];
  __syncthreads();
#pragma unroll
  for (int g = 0; g < 3; ++g) {
    f32x4 a = pacc[wave][g];
#pragma unroll
    for (int sw = 0; sw < 4; ++sw)
      if (sw != wave)
#pragma unroll
        for (int r = 0; r < 4; ++r)
          a[r] += red[(((sw * 4 + wave) * 3 + g) * 4 + r) * 64 + lane];
    acc[g] = a;
  }
}

__global__ __launch_bounds__(256, 1) void gru_main(
    const float* __restrict__ x, const float* __restrict__ xmask,
    const float* __restrict__ h0in,
    const float* __restrict__ Wih0, const float* __restrict__ Whh0,
    const float* __restrict__ bih0, const float* __restrict__ bhh0,
    const float* __restrict__ Wih1, const float* __restrict__ Whh1,
    const float* __restrict__ bih1, const float* __restrict__ bhh1,
    float* __restrict__ out, GruWS* __restrict__ ws) {
  __shared__ __align__(16) char ldsbuf[49152];
  float* red = (float*)ldsbuf;

  const int bid = blockIdx.x;
  const int grp = bid >> 5;         // 0:L0gi 1:L0gh 2:L1gi 3:L1gh
  const int gidx = bid & 31;
  const int base = gidx * 32;
  const int tid = threadIdx.x;
  const int lane = tid & 63;
  const int wave = tid >> 6;
  const int l15 = lane & 15;
  const int kgrp = lane >> 4;
  const int b0 = wave * 16 + kgrp * 4;
  const int kbase0 = wave * 256 + kgrp * 8;
  unsigned* sig = ws->sigT;

  const float* Wsrc = (grp == 0) ? Wih0 : (grp == 1) ? Whh0 : (grp == 2) ? Wih1 : Whh1;
  f16x8 breg[2][3][8];
#pragma unroll
  for (int nt = 0; nt < 2; ++nt)
#pragma unroll
    for (int g = 0; g < 3; ++g)
#pragma unroll
      for (int kk = 0; kk < 8; ++kk) {
        const float* p = Wsrc + (long)(g * HH + base + nt * 16 + l15) * DD + kbase0 + kk * 32;
        float4 v0 = *(const float4*)p;
        float4 v1 = *(const float4*)(p + 4);
        f16x8 t;
        t[0] = (f16)v0.x; t[1] = (f16)v0.y; t[2] = (f16)v0.z; t[3] = (f16)v0.w;
        t[4] = (f16)v1.x; t[5] = (f16)v1.y; t[6] = (f16)v1.z; t[7] = (f16)v1.w;
        breg[nt][g][kk] = t;
      }

  if (grp == 0 || grp == 2) {
    // ============ gi roles ============
    const int layer = (grp == 2);
    const float* bih = layer ? bih1 : bih0;
    const float* bhh = layer ? bhh1 : bhh0;
    float bias[2][3];
#pragma unroll
    for (int nt = 0; nt < 2; ++nt)
#pragma unroll
      for (int g = 0; g < 3; ++g) {
        int colg = base + nt * 16 + l15;
        bias[nt][g] = bih[g * HH + colg] + (g < 2 ? bhh[g * HH + colg] : 0.0f);
      }
    int seen_slot = 0, seen_h = 0;

    for (int s = 0; s < SS; ++s) {
      if (!layer) {
        if (wave == 0) wait1(&sig[(1 * 32 + gidx) * 16], s - 3, seen_slot);
      } else {
        if (wave == 0) wait32(&sig[1 * 32 * 16], s + 1, lane, seen_h);        // h0(s) ready
        if (wave == 1) wait1(&sig[(3 * 32 + gidx) * 16], s - 3, seen_slot);
      }
      __syncthreads();
      if ((s & 31) == 0) __threadfence();   // epoch L2 invalidate (stale h-slot copies)
      {
        f16x8 areg[8][4];
        if (!layer) {
#pragma unroll
          for (int kk = 0; kk < 8; ++kk)
#pragma unroll
            for (int m = 0; m < 4; ++m) {
              const float* p = x + (long)(m * 16 + l15) * (SS * DD) + (long)s * DD + kbase0 + kk * 32;
              float4 v0 = *(const float4*)p;
              float4 v1 = *(const float4*)(p + 4);
              f16x8 a;
              a[0] = (f16)v0.x; a[1] = (f16)v0.y; a[2] = (f16)v0.z; a[3] = (f16)v0.w;
              a[4] = (f16)v1.x; a[5] = (f16)v1.y; a[6] = (f16)v1.z; a[7] = (f16)v1.w;
              areg[kk][m] = a;
            }
        } else {
          const f16* A = &ws->h0h[s & HMASK][0][0];
#pragma unroll
          for (int kk = 0; kk < 8; ++kk)
#pragma unroll
            for (int m = 0; m < 4; ++m)
              areg[kk][m] = ld_dev_16B(A + (long)(m * 16 + l15) * HH + kbase0 + kk * 32);
          drain_vm();
        }
        f32x4 accs[2][3];
        mma_pass(areg, &breg[0][0][0], red, lane, wave, accs[0]);
        __syncthreads();
        mma_pass(areg, &breg[1][0][0], red, lane, wave, accs[1]);
        __syncthreads();

        f16* gt = (f16*)ldsbuf;   // [96][64]
#pragma unroll
        for (int nt = 0; nt < 2; ++nt)
#pragma unroll
          for (int g = 0; g < 3; ++g) {
            f16x4 o;
#pragma unroll
            for (int r = 0; r < 4; ++r) o[r] = (f16)(accs[nt][g][r] + bias[nt][g]);
            *(f16x4*)(gt + (g * 32 + nt * 16 + l15) * 64 + b0) = o;
          }
        __syncthreads();
        f16* gib = layer ? &ws->gi1[s & 3][0][0] : &ws->gi0[s & 3][0][0];
#pragma unroll
        for (int rnd = 0; rnd < 3; ++rnd) {
          int idx = rnd * 256 + tid;
          int row = idx >> 3, ch = idx & 7;
          int g = row >> 5, c = row & 31;
          f16x8 v = *(const f16x8*)(gt + row * 64 + ch * 8);
          st_sys_16B(gib + (long)(g * HH + base + c) * BB + ch * 8, v);
        }
      }
      asm volatile("s_waitcnt vmcnt(0)" ::: "memory");
      __syncthreads();
      if (tid == 0) sig_swap(&sig[(grp * 32 + gidx) * 16], (unsigned)(s + 1));
    }
  } else {
    // ============ gh roles ============
    const int layer = (grp == 3);
    const float* bhh = layer ? bhh1 : bhh0;
    float bhn[2], hold[2][4], osum[2][4];
#pragma unroll
    for (int nt = 0; nt < 2; ++nt) {
      bhn[nt] = bhh[2 * HH + base + nt * 16 + l15];
#pragma unroll
      for (int r = 0; r < 4; ++r) {
        hold[nt][r] = h0in[(long)layer * BB * HH + (long)(b0 + r) * HH + base + nt * 16 + l15];
        osum[nt][r] = 0.f;
      }
    }
    int seen_gi = 0, seen_peers = 0, seen_cons = 0;
    u64 ta = 0, tb = 0, tc = 0, td = 0;

    for (int s = 0; s < SS; ++s) {
      u64 t0 = __builtin_amdgcn_s_memrealtime();
      float mv[4];
#pragma unroll
      for (int r = 0; r < 4; ++r) mv[r] = xmask[(long)(b0 + r) * SS + s];
      if (!layer) {
        if (wave == 0) wait32(&sig[1 * 32 * 16], s, lane, seen_peers);        // peers h0(s-1)
        if (wave == 1) wait1(&sig[(0 * 32 + gidx) * 16], s + 1, seen_gi);     // gi0(s)
        if (wave == 2) wait32(&sig[2 * 32 * 16], s - 60, lane, seen_cons);    // h0 slot reuse guard
      } else {
        if (wave == 0) wait1(&sig[(2 * 32 + gidx) * 16], s + 1, seen_gi);     // gi1(s)
        if (wave == 1) wait32(&sig[3 * 32 * 16], s, lane, seen_peers);        // peers h1(s-1)
      }
      __syncthreads();
      if ((s & 31) == 0) __threadfence();   // epoch L2 invalidate
      u64 t1 = __builtin_amdgcn_s_memrealtime();
      {
        const f16* hprev = layer ? &ws->h1h[(s - 1) & HMASK][0][0] : &ws->h0h[(s - 1) & HMASK][0][0];
        const f16* gib = layer ? &ws->gi1[s & 3][0][0] : &ws->gi0[s & 3][0][0];
        f16x8 areg[8][4];
#pragma unroll
        for (int kk = 0; kk < 8; ++kk)
#pragma unroll
          for (int m = 0; m < 4; ++m)
            areg[kk][m] = ld_dev_16B(hprev + (long)(m * 16 + l15) * HH + kbase0 + kk * 32);
        f16x4 gfr[2][3];
#pragma unroll
        for (int nt = 0; nt < 2; ++nt)
#pragma unroll
          for (int g = 0; g < 3; ++g)
            gfr[nt][g] = ld_sys_f16x4(gib + (long)(g * HH + base + nt * 16 + l15) * BB + b0);
        drain_vm();
        u64 t2 = __builtin_amdgcn_s_memrealtime();

        f32x4 accs[2][3];
        mma_pass(areg, &breg[0][0][0], red, lane, wave, accs[0]);
        __syncthreads();
        mma_pass(areg, &breg[1][0][0], red, lane, wave, accs[1]);
        __syncthreads();

        f16* htile = (f16*)ldsbuf;  // [64][32]
#pragma unroll
        for (int nt = 0; nt < 2; ++nt)
#pragma unroll
          for (int r = 0; r < 4; ++r) {
            float pr = accs[nt][0][r] + (float)gfr[nt][0][r];
            float pz = accs[nt][1][r] + (float)gfr[nt][1][r];
            float ph = accs[nt][2][r] + bhn[nt];
            float rr = 1.0f / (1.0f + __expf(-pr));
            float zz = 1.0f / (1.0f + __expf(-pz));
            float nn = tanhf((float)gfr[nt][2][r] + rr * ph);
            float upd = hold[nt][r] + (1.0f - zz) * (nn - hold[nt][r]);
            if (mv[r] > 0.5f) {
              hold[nt][r] = upd;
              if (layer) osum[nt][r] += upd;
            }
            htile[(b0 + r) * 32 + nt * 16 + l15] = (f16)hold[nt][r];
          }
        __syncthreads();
        u64 t3 = __builtin_amdgcn_s_memrealtime();
        f16* hout = layer ? &ws->h1h[s & HMASK][0][0] : &ws->h0h[s & HMASK][0][0];
        {
          int b = tid >> 2, ch = tid & 3;
          f16x8 v = *(const f16x8*)(htile + b * 32 + ch * 8);
          st_mall_16B(hout + (long)b * HH + base + ch * 8, v);
        }
        if (s == SS - 1 && layer) {
#pragma unroll
          for (int nt = 0; nt < 2; ++nt)
#pragma unroll
            for (int r = 0; r < 4; ++r) {
              int colg = base + nt * 16 + l15;
              float h0f = ld_sys_f16s(&ws->h0h[HMASK][b0 + r][colg]);  // h0(511) in slot 63
              out[(long)(b0 + r) * HH + colg] =
                  (osum[nt][r] + hold[nt][r] + h0f) * (1.0f / 514.0f);
            }
        }
        asm volatile("s_waitcnt vmcnt(0)" ::: "memory");
        __syncthreads();
        if (tid == 0) sig_swap(&sig[(grp * 32 + gidx) * 16], (unsigned)(s + 1));
        u64 t4 = __builtin_amdgcn_s_memrealtime();
        if (tid == 0) { ta += t1 - t0; tb += t2 - t1; tc += t3 - t2; td += t4 - t3; }
      }
    }
    if (!layer && tid == 0) {
      st_sys_8B_u64(&ws->times[0 * 32 + gidx], ta);
      st_sys_8B_u64(&ws->times[1 * 32 + gidx], tb);
      st_sys_8B_u64(&ws->times[2 * 32 + gidx], tc);
      st_sys_8B_u64(&ws->times[3 * 32 + gidx], td);
      asm volatile("s_waitcnt vmcnt(0)" ::: "memory");
    }
  }
}

extern "C" void kernel_launch(void* const* d_in, const int* in_sizes, int n_in,
                              void* d_out, int out_size, void* d_ws, size_t ws_size,
                              hipStream_t stream) {
  const float* x = (const float*)d_in[0];
  const float* xmask = (const float*)d_in[1];
  const float* h0 = (const float*)d_in[2];
  const float* Wih0 = (const float*)d_in[3];
  const float* Whh0 = (const float*)d_in[4];
  const float* bih0 = (const float*)d_in[5];
  const float* bhh0 = (const float*)d_in[6];
  const float* Wih1 = (const float*)d_in[7];
  const float* Whh1 = (const float*)d_in[8];
  const float* bih1 = (const float*)d_in[9];
  const float* bhh1 = (const float*)d_in[10];
  float* out = (float*)d_out;
  GruWS* ws = (GruWS*)d_ws;

  hipLaunchKernelGGL(gru_init, dim3(128), dim3(256), 0, stream, h0, ws);
  hipLaunchKernelGGL(gru_main, dim3(NBLK), dim3(256), 0, stream,
                     x, xmask, h0, Wih0, Whh0, bih0, bhh0,
                     Wih1, Whh1, bih1, bhh1, out, ws);
  for (int p = 0; p < 4; ++p)
    hipLaunchKernelGGL(spin_probe, dim3(1), dim3(64), 0, stream, (const GruWS*)ws, p);
}

// Round 11
// 9311.356 us; speedup vs baseline: 4.5654x; 4.5654x over previous
//
#include <hip/hip_runtime.h>
#include <hip/hip_fp16.h>

#define BB 64
#define SS 512
#define DD 1024
#define HH 1024
#define NBLK 128
#define HMASK 63

typedef _Float16 f16;
typedef unsigned long long u64;
typedef __attribute__((ext_vector_type(8))) _Float16 f16x8;
typedef __attribute__((ext_vector_type(4))) _Float16 f16x4;
typedef __attribute__((ext_vector_type(4))) float f32x4;

struct GruWS {
  unsigned sigT[4 * 32 * 16];   // per-(role,member) signal line (64B); value = completed s+1, monotone
  f16 gi0[4][3 * HH][BB];       // [slot s&3][3H][B]  (MALL path, single consumer per column-slice)
  f16 gi1[4][3 * HH][BB];
  f16 h0h[64][BB][HH];          // [slot s&63][B][H]  (atomic-swap stores, sc0-cached reads)
  f16 h1h[64][BB][HH];
};

// ---- communication primitives ----
__device__ __forceinline__ f16x8 ld_dev_16B(const void* p) {          // L2-cached, L1-bypass
  f16x8 r;
  asm volatile("global_load_dwordx4 %0, %1, off sc0" : "=v"(r) : "v"(p) : "memory");
  return r;
}
__device__ __forceinline__ void st_sys_16B(void* p, f16x8 v) {
  asm volatile("global_store_dwordx4 %0, %1, off sc0 sc1" :: "v"(p), "v"(v) : "memory");
}
// h stores: atomic swaps execute AT the MALL -> line stays resident for readers' L2 refills
__device__ __forceinline__ void st_mall_16B(void* p, f16x8 v) {
  union { f16x8 v; u64 q[2]; } u; u.v = v;
  asm volatile("global_atomic_swap_x2 %0, %1, off sc1" :: "v"((u64*)p), "v"(u.q[0]) : "memory");
  asm volatile("global_atomic_swap_x2 %0, %1, off sc1" :: "v"((u64*)p + 1), "v"(u.q[1]) : "memory");
}
__device__ __forceinline__ void st_mall_8B(void* p, u64 q) {
  asm volatile("global_atomic_swap_x2 %0, %1, off sc1" :: "v"((u64*)p), "v"(q) : "memory");
}
__device__ __forceinline__ void sig_swap(unsigned* p, unsigned v) {
  asm volatile("global_atomic_swap %0, %1, off sc1" :: "v"(p), "v"(v) : "memory");
}
__device__ __forceinline__ void drain_vm() {
  asm volatile("s_waitcnt vmcnt(0)" ::: "memory");
  __builtin_amdgcn_sched_barrier(0);
}
__device__ __forceinline__ f16x4 ld_sys_f16x4(const f16* p) {
  u64 q = __hip_atomic_load((const u64*)p, __ATOMIC_RELAXED, __HIP_MEMORY_SCOPE_SYSTEM);
  union { u64 q; f16x4 v; } u; u.q = q; return u.v;
}
__device__ __forceinline__ float ld_sys_f16s(const f16* p) {
  unsigned short s = __hip_atomic_load((const unsigned short*)p, __ATOMIC_RELAXED, __HIP_MEMORY_SCOPE_SYSTEM);
  union { unsigned short s; f16 h; } u; u.s = s; return (float)u.h;
}
__device__ __forceinline__ void st_sys_u16(f16* p, f16 v) {
  union { f16 h; unsigned short s; } u; u.h = v;
  __hip_atomic_store((unsigned short*)p, u.s, __ATOMIC_RELAXED, __HIP_MEMORY_SCOPE_SYSTEM);
}
__device__ __forceinline__ void nap(int it) {
  if (it < 3) __builtin_amdgcn_s_sleep(1);
  else        __builtin_amdgcn_s_sleep(16);
}

// single-line wait (one producer), with seen-cache + backoff
__device__ __forceinline__ void wait1(const unsigned* p, int target, int& seen) {
  if (target <= 0 || seen >= target) return;
  int it = 0;
  for (;;) {
    unsigned v;
    asm volatile("global_load_dword %0, %1, off sc0 sc1" : "=v"(v) : "v"(p));
    asm volatile("s_waitcnt vmcnt(0)" ::: "memory");
    if ((int)v >= target) { seen = (int)v; break; }
    nap(++it);
  }
  asm volatile("" ::: "memory");
}

// role-wide wait: ALL 32 members >= target (rare guards only)
__device__ __forceinline__ void wait32(const unsigned* rowbase, int target, int lane, int& seen) {
  if (target <= 0 || seen >= target) return;
  const unsigned* p = rowbase + (lane & 31) * 16;
  int it = 0;
  unsigned v;
  for (;;) {
    asm volatile("global_load_dword %0, %1, off sc0 sc1" : "=v"(v) : "v"(p));
    asm volatile("s_waitcnt vmcnt(0)" ::: "memory");
    if (__all((int)v >= target)) break;
    nap(++it);
  }
  int m = (int)v;
#pragma unroll
  for (int off = 1; off < 32; off <<= 1) {
    int o = __shfl_xor(m, off);
    m = (o < m) ? o : m;
  }
  seen = m;
  asm volatile("" ::: "memory");
}

// HOT per-wave wait: lanes 0-7 poll this wave's 8 h-producers (hbase + wv*8 + lane),
// lane 8 polls the gi line (if any). Returns when all satisfied; updates seen-caches.
__device__ __forceinline__ void wait_hot8(const unsigned* sig, int hbase, int wv,
                                          int htgt, int giline, int gitgt,
                                          int lane, int& seenh, int& seengi) {
  const bool needh = (htgt > 0) && (seenh < htgt);
  const bool needg = (giline >= 0) && (seengi < gitgt);
  if (!needh && !needg) return;
  const bool isgi = (lane == 8) && (giline >= 0);
  const unsigned* p = sig + ((isgi ? giline : (hbase + wv * 8 + (lane & 7))) << 4);
  const int tgt = isgi ? gitgt : htgt;
  int it = 0;
  unsigned v;
  for (;;) {
    asm volatile("global_load_dword %0, %1, off sc0 sc1" : "=v"(v) : "v"(p));
    asm volatile("s_waitcnt vmcnt(0)" ::: "memory");
    if (__all((int)v >= tgt)) break;
    nap(++it);
  }
  int m = (int)v;
#pragma unroll
  for (int off = 1; off < 8; off <<= 1) {      // min over lanes 0..7 (h lines)
    int o = __shfl_xor(m, off);
    m = (o < m) ? o : m;
  }
  int hmin = __shfl(m, 0);
  int gv = __shfl((int)v, 8);
  if (htgt > 0) seenh = hmin;
  if (giline >= 0) seengi = gv;
  asm volatile("" ::: "memory");
}

__global__ void gru_init(const float* __restrict__ h0, GruWS* __restrict__ ws) {
  int i = blockIdx.x * 256 + threadIdx.x;
  int j = i * 4;
  if (j < 2 * BB * HH) {
    union { f16 h[4]; u64 q; } u;
#pragma unroll
    for (int k = 0; k < 4; ++k) u.h[k] = (f16)h0[j + k];
    if (j < BB * HH) st_mall_8B(&ws->h0h[HMASK][0][j], u.q);          // slot 63 = state of s=-1
    else             st_mall_8B(&ws->h1h[HMASK][0][j - BB * HH], u.q);
  }
  if (i < 4 * 32)
    __hip_atomic_store(&ws->sigT[i * 16], 0u, __ATOMIC_RELAXED, __HIP_MEMORY_SCOPE_SYSTEM);
}

// per-wave K-quarter MFMA + cross-wave LDS K-reduce (syncthreads inside)
__device__ __forceinline__ void mma_pass(const f16x8 areg[8][4], const f16x8* bnt,
                                         float* red, int lane, int wave, f32x4 acc[3]) {
  f32x4 pacc[4][3];
#pragma unroll
  for (int m = 0; m < 4; ++m)
#pragma unroll
    for (int g = 0; g < 3; ++g) pacc[m][g] = (f32x4){0.f, 0.f, 0.f, 0.f};
#pragma unroll
  for (int kk = 0; kk < 8; ++kk)
#pragma unroll
    for (int m = 0; m < 4; ++m)
#pragma unroll
      for (int g = 0; g < 3; ++g)
        pacc[m][g] = __builtin_amdgcn_mfma_f32_16x16x32_f16(areg[kk][m], bnt[g * 8 + kk], pacc[m][g], 0, 0, 0);
#pragma unroll
  for (int m = 0; m < 4; ++m)
    if (m != wave)
#pragma unroll
      for (int g = 0; g < 3; ++g)
#pragma unroll
        for (int r = 0; r < 4; ++r)
          red[(((wave * 4 + m) * 3 + g) * 4 + r) * 64 + lane] = pacc[m][g][r];
  __syncthreads();
#pragma unroll
  for (int g = 0; g < 3; ++g) {
    f32x4 a = pacc[wave][g];
#pragma unroll
    for (int sw = 0; sw < 4; ++sw)
      if (sw != wave)
#pragma unroll
        for (int r = 0; r < 4; ++r)
          a[r] += red[(((sw * 4 + wave) * 3 + g) * 4 + r) * 64 + lane];
    acc[g] = a;
  }
}

__global__ __launch_bounds__(256, 1) void gru_main(
    const float* __restrict__ x, const float* __restrict__ xmask,
    const float* __restrict__ h0in,
    const float* __restrict__ Wih0, const float* __restrict__ Whh0,
    const float* __restrict__ bih0, const float* __restrict__ bhh0,
    const float* __restrict__ Wih1, const float* __restrict__ Whh1,
    const float* __restrict__ bih1, const float* __restrict__ bhh1,
    float* __restrict__ out, GruWS* __restrict__ ws) {
  __shared__ __align__(16) char ldsbuf[49152];
  float* red = (float*)ldsbuf;

  const int bid = blockIdx.x;
  const int grp = bid >> 5;         // 0:L0gi 1:L0gh 2:L1gi 3:L1gh
  const int gidx = bid & 31;
  const int base = gidx * 32;
  const int tid = threadIdx.x;
  const int lane = tid & 63;
  const int wave = tid >> 6;
  const int l15 = lane & 15;
  const int kgrp = lane >> 4;
  const int b0 = wave * 16 + kgrp * 4;
  const int kbase0 = wave * 256 + kgrp * 8;
  unsigned* sig = ws->sigT;
  unsigned* mysig = &sig[(grp * 32 + gidx) * 16];

  const float* Wsrc = (grp == 0) ? Wih0 : (grp == 1) ? Whh0 : (grp == 2) ? Wih1 : Whh1;
  f16x8 breg[2][3][8];
#pragma unroll
  for (int nt = 0; nt < 2; ++nt)
#pragma unroll
    for (int g = 0; g < 3; ++g)
#pragma unroll
      for (int kk = 0; kk < 8; ++kk) {
        const float* p = Wsrc + (long)(g * HH + base + nt * 16 + l15) * DD + kbase0 + kk * 32;
        float4 v0 = *(const float4*)p;
        float4 v1 = *(const float4*)(p + 4);
        f16x8 t;
        t[0] = (f16)v0.x; t[1] = (f16)v0.y; t[2] = (f16)v0.z; t[3] = (f16)v0.w;
        t[4] = (f16)v1.x; t[5] = (f16)v1.y; t[6] = (f16)v1.z; t[7] = (f16)v1.w;
        breg[nt][g][kk] = t;
      }

  if (grp == 0 || grp == 2) {
    // ============ gi roles: gi = A @ Wih^T + (bih + bhh_{r,z}) ============
    const int layer = (grp == 2);
    const float* bih = layer ? bih1 : bih0;
    const float* bhh = layer ? bhh1 : bhh0;
    float bias[2][3];
#pragma unroll
    for (int nt = 0; nt < 2; ++nt)
#pragma unroll
      for (int g = 0; g < 3; ++g) {
        int colg = base + nt * 16 + l15;
        bias[nt][g] = bih[g * HH + colg] + (g < 2 ? bhh[g * HH + colg] : 0.0f);
      }
    int seen_slot = 0, seen_h = 0, dum = 0;

    for (int s = 0; s < SS; ++s) {
      // per-wave waits (no block barrier; mma_pass's syncthreads re-converges)
      if (!layer) {
        wait1(&sig[(1 * 32 + gidx) * 16], s - 3, seen_slot);          // gi0 slot free (rare)
      } else {
        wait1(&sig[(3 * 32 + gidx) * 16], s - 3, seen_slot);          // gi1 slot free (rare)
        wait_hot8(sig, 1 * 32, wave, s + 1, -1, 0, lane, seen_h, dum); // h0(s) ready (this wave's 8 producers)
      }
      if ((s & 31) == 0) __threadfence();   // epoch L2 invalidate
      {
        f16x8 areg[8][4];
        if (!layer) {
#pragma unroll
          for (int kk = 0; kk < 8; ++kk)
#pragma unroll
            for (int m = 0; m < 4; ++m) {
              const float* p = x + (long)(m * 16 + l15) * (SS * DD) + (long)s * DD + kbase0 + kk * 32;
              float4 v0 = *(const float4*)p;
              float4 v1 = *(const float4*)(p + 4);
              f16x8 a;
              a[0] = (f16)v0.x; a[1] = (f16)v0.y; a[2] = (f16)v0.z; a[3] = (f16)v0.w;
              a[4] = (f16)v1.x; a[5] = (f16)v1.y; a[6] = (f16)v1.z; a[7] = (f16)v1.w;
              areg[kk][m] = a;
            }
        } else {
          const f16* A = &ws->h0h[s & HMASK][0][0];
#pragma unroll
          for (int kk = 0; kk < 8; ++kk)
#pragma unroll
            for (int m = 0; m < 4; ++m)
              areg[kk][m] = ld_dev_16B(A + (long)(m * 16 + l15) * HH + kbase0 + kk * 32);
        }
        drain_vm();
        f32x4 accs[2][3];
        mma_pass(areg, &breg[0][0][0], red, lane, wave, accs[0]);
        __syncthreads();  // WAR on red
        mma_pass(areg, &breg[1][0][0], red, lane, wave, accs[1]);
        __syncthreads();  // red dead -> gt alias

        f16* gt = (f16*)ldsbuf;   // [96][64]
#pragma unroll
        for (int nt = 0; nt < 2; ++nt)
#pragma unroll
          for (int g = 0; g < 3; ++g) {
            f16x4 o;
#pragma unroll
            for (int r = 0; r < 4; ++r) o[r] = (f16)(accs[nt][g][r] + bias[nt][g]);
            *(f16x4*)(gt + (g * 32 + nt * 16 + l15) * 64 + b0) = o;
          }
        __syncthreads();
        f16* gib = layer ? &ws->gi1[s & 3][0][0] : &ws->gi0[s & 3][0][0];
#pragma unroll
        for (int rnd = 0; rnd < 3; ++rnd) {
          int idx = rnd * 256 + tid;
          int row = idx >> 3, ch = idx & 7;
          int g = row >> 5, c = row & 31;
          f16x8 v = *(const f16x8*)(gt + row * 64 + ch * 8);
          st_sys_16B(gib + (long)(g * HH + base + c) * BB + ch * 8, v);
        }
      }
      asm volatile("s_waitcnt vmcnt(0)" ::: "memory");
      __syncthreads();
      if (tid == 0) sig_swap(mysig, (unsigned)(s + 1));
    }
  } else {
    // ============ gh roles: recurrent step ============
    const int layer = (grp == 3);
    const float* bhh = layer ? bhh1 : bhh0;
    float bhn[2], hold[2][4], osum[2][4];
#pragma unroll
    for (int nt = 0; nt < 2; ++nt) {
      bhn[nt] = bhh[2 * HH + base + nt * 16 + l15];
#pragma unroll
      for (int r = 0; r < 4; ++r) {
        hold[nt][r] = h0in[(long)layer * BB * HH + (long)(b0 + r) * HH + base + nt * 16 + l15];
        osum[nt][r] = 0.f;
      }
    }
    int seen_gi = 0, seen_peers = 0, seen_cons = 0;

    for (int s = 0; s < SS; ++s) {
      float mv[4];
#pragma unroll
      for (int r = 0; r < 4; ++r) mv[r] = xmask[(long)(b0 + r) * SS + s];
      // per-wave waits
      if (!layer) {
        wait32(&sig[2 * 32 * 16], s - 60, lane, seen_cons);            // h0 slot reuse guard (rare)
        wait_hot8(sig, 1 * 32, wave, s, 0 * 32 + gidx, s + 1, lane, seen_peers, seen_gi);
      } else {
        wait_hot8(sig, 3 * 32, wave, s, 2 * 32 + gidx, s + 1, lane, seen_peers, seen_gi);
      }
      if ((s & 31) == 0) __threadfence();   // epoch L2 invalidate
      {
        const f16* hprev = layer ? &ws->h1h[(s - 1) & HMASK][0][0] : &ws->h0h[(s - 1) & HMASK][0][0];
        const f16* gib = layer ? &ws->gi1[s & 3][0][0] : &ws->gi0[s & 3][0][0];
        f16x8 areg[8][4];
#pragma unroll
        for (int kk = 0; kk < 8; ++kk)
#pragma unroll
          for (int m = 0; m < 4; ++m)
            areg[kk][m] = ld_dev_16B(hprev + (long)(m * 16 + l15) * HH + kbase0 + kk * 32);
        f16x4 gfr[2][3];
#pragma unroll
        for (int nt = 0; nt < 2; ++nt)
#pragma unroll
          for (int g = 0; g < 3; ++g)
            gfr[nt][g] = ld_sys_f16x4(gib + (long)(g * HH + base + nt * 16 + l15) * BB + b0);
        drain_vm();

        f32x4 accs[2][3];
        mma_pass(areg, &breg[0][0][0], red, lane, wave, accs[0]);
        __syncthreads();
        mma_pass(areg, &breg[1][0][0], red, lane, wave, accs[1]);
        __syncthreads();

        f16* htile = (f16*)ldsbuf;  // [64][32]
#pragma unroll
        for (int nt = 0; nt < 2; ++nt)
#pragma unroll
          for (int r = 0; r < 4; ++r) {
            float pr = accs[nt][0][r] + (float)gfr[nt][0][r];
            float pz = accs[nt][1][r] + (float)gfr[nt][1][r];
            float ph = accs[nt][2][r] + bhn[nt];
            float rr = 1.0f / (1.0f + __expf(-pr));
            float zz = 1.0f / (1.0f + __expf(-pz));
            float nn = tanhf((float)gfr[nt][2][r] + rr * ph);
            float upd = hold[nt][r] + (1.0f - zz) * (nn - hold[nt][r]);
            if (mv[r] > 0.5f) {
              hold[nt][r] = upd;
              if (layer) osum[nt][r] += upd;
            }
            htile[(b0 + r) * 32 + nt * 16 + l15] = (f16)hold[nt][r];
          }
        __syncthreads();
        f16* hout = layer ? &ws->h1h[s & HMASK][0][0] : &ws->h0h[s & HMASK][0][0];
        {
          int b = tid >> 2, ch = tid & 3;
          f16x8 v = *(const f16x8*)(htile + b * 32 + ch * 8);
          st_mall_16B(hout + (long)b * HH + base + ch * 8, v);
        }
        if (s == SS - 1 && layer) {
#pragma unroll
          for (int nt = 0; nt < 2; ++nt)
#pragma unroll
            for (int r = 0; r < 4; ++r) {
              int colg = base + nt * 16 + l15;
              float h0f = ld_sys_f16s(&ws->h0h[HMASK][b0 + r][colg]);  // h0(511) in slot 63
              out[(long)(b0 + r) * HH + colg] =
                  (osum[nt][r] + hold[nt][r] + h0f) * (1.0f / 514.0f);
            }
        }
      }
      asm volatile("s_waitcnt vmcnt(0)" ::: "memory");
      __syncthreads();
      if (tid == 0) sig_swap(mysig, (unsigned)(s + 1));
    }
  }
}

extern "C" void kernel_launch(void* const* d_in, const int* in_sizes, int n_in,
                              void* d_out, int out_size, void* d_ws, size_t ws_size,
                              hipStream_t stream) {
  const float* x = (const float*)d_in[0];
  const float* xmask = (const float*)d_in[1];
  const float* h0 = (const float*)d_in[2];
  const float* Wih0 = (const float*)d_in[3];
  const float* Whh0 = (const float*)d_in[4];
  const float* bih0 = (const float*)d_in[5];
  const float* bhh0 = (const float*)d_in[6];
  const float* Wih1 = (const float*)d_in[7];
  const float* Whh1 = (const float*)d_in[8];
  const float* bih1 = (const float*)d_in[9];
  const float* bhh1 = (const float*)d_in[10];
  float* out = (float*)d_out;
  GruWS* ws = (GruWS*)d_ws;

  hipLaunchKernelGGL(gru_init, dim3(128), dim3(256), 0, stream, h0, ws);
  hipLaunchKernelGGL(gru_main, dim3(NBLK), dim3(256), 0, stream,
                     x, xmask, h0, Wih0, Whh0, bih0, bhh0,
                     Wih1, Whh1, bih1, bhh1, out, ws);
}